// Round 2
// 730.576 us; speedup vs baseline: 1.1236x; 1.1236x over previous
//
#include <hip/hip_runtime.h>
#include <hip/hip_bf16.h>
#include <stdint.h>
#include <stddef.h>

typedef __attribute__((ext_vector_type(8))) short bf16x8;
typedef __attribute__((ext_vector_type(4))) short bf16x4;
typedef __attribute__((ext_vector_type(4))) float f32x4;

__device__ __forceinline__ unsigned short f2bf(float x) {
    union { float f; unsigned u; } v; v.f = x;
    unsigned r = v.u + 0x7fffu + ((v.u >> 16) & 1u);   // round-to-nearest-even
    return (unsigned short)(r >> 16);
}
__device__ __forceinline__ float bf2f(unsigned short h) {
    union { unsigned u; float f; } v; v.u = ((unsigned)h) << 16;
    return v.f;
}

// ---- transpose + convert weights: WT[n][k] = bf16(W[k][n]) ----
extern "C" __global__ void prep_w_kernel(const float* __restrict__ Wp, const float* __restrict__ Ws,
                                         unsigned short* __restrict__ WpT, unsigned short* __restrict__ WsT,
                                         int Cin, int Cs, int Cout)
{
    int tid = blockIdx.x * blockDim.x + threadIdx.x;
    int np = Cin * Cout;
    int ns = Cs * Cout;
    if (tid < np) {
        int k = tid / Cout, n = tid - k * Cout;
        WpT[n * Cin + k] = f2bf(Wp[tid]);
    } else if (tid < np + ns) {
        int t = tid - np;
        int k = t / Cout, n = t - k * Cout;
        WsT[n * Cs + k] = f2bf(Ws[t]);
    }
}

// ---- 128x128 bf16 MFMA GEMM: outb = bf16(A @ W + bias), per-block channel partial sums ----
// A: [M,K] fp32 row-major.  WT: [N,K] bf16.  outb: [M,N] bf16.
// Ppart: [M/128][2][N] fp32 per-row-block partial (sum, sumsq) -- written non-atomically.
// grid = (N/128, M/128), block = 256 (4 waves; wave w covers 64x64 at (w>>1, w&1)).
// SWAPPED mfma operands: D[n][m] -> lane holds m = lane&15, channels = (lane>>4)*4 + reg.
extern "C" __global__ __launch_bounds__(256, 2)
void gemm_bn_kernel(const float* __restrict__ A, const unsigned short* __restrict__ WT,
                    const float* __restrict__ bias,
                    unsigned short* __restrict__ outb,
                    float* __restrict__ Ppart,
                    int M, int K, int N)
{
    const int m0 = blockIdx.y * 128;
    const int n0 = blockIdx.x * 128;
    const int tid = threadIdx.x;
    const int lane = tid & 63;
    const int wave = tid >> 6;
    const int wm = (wave >> 1) << 6;
    const int wn = (wave & 1) << 6;
    const int q = lane >> 4;       // quad index 0..3
    const int l15 = lane & 15;

    // unpadded 64B rows (m97 layout): b128 frag reads sit at the structural phase floor
    __shared__ unsigned short sA[128 * 32];
    __shared__ unsigned short sB[128 * 32];

    f32x4 acc[4][4];
#pragma unroll
    for (int i = 0; i < 4; ++i)
#pragma unroll
        for (int j = 0; j < 4; ++j)
            acc[i][j] = (f32x4){0.f, 0.f, 0.f, 0.f};

    // A staging: thread t -> row a_r (+32r), float4 col a_f (coalesced 8 rows x 128B per wave)
    const int a_r = tid >> 3;      // 0..31
    const int a_f = tid & 7;       // 0..7
    // B staging: thread t -> row b_r (+64r), bf16x8 seg b_s
    const int b_r = tid >> 2;      // 0..63
    const int b_s = tid & 3;       // 0..3

    const float* Ap0 = A + (size_t)(m0 + a_r) * K + a_f * 4;
    const unsigned short* Bp0 = WT + (size_t)(n0 + b_r) * K + b_s * 8;

    const int ksteps = K >> 5;

    // register prefetch buffers (tile kt held here while tile kt-1 computes)
    f32x4 ar[4];
    bf16x8 br[2];
#pragma unroll
    for (int r = 0; r < 4; ++r) ar[r] = *(const f32x4*)(Ap0 + (size_t)(32 * r) * K);
#pragma unroll
    for (int r = 0; r < 2; ++r) br[r] = *(const bf16x8*)(Bp0 + (size_t)(64 * r) * K);

    for (int kt = 0; kt < ksteps; ++kt) {
        __syncthreads();   // (a) prev frag reads done; prefetch loads for this tile drained here
#pragma unroll
        for (int r = 0; r < 4; ++r) {
            bf16x4 pk;
            pk[0] = (short)f2bf(ar[r][0]); pk[1] = (short)f2bf(ar[r][1]);
            pk[2] = (short)f2bf(ar[r][2]); pk[3] = (short)f2bf(ar[r][3]);
            *(bf16x4*)(&sA[(a_r + 32 * r) * 32 + a_f * 4]) = pk;
        }
#pragma unroll
        for (int r = 0; r < 2; ++r)
            *(bf16x8*)(&sB[(b_r + 64 * r) * 32 + b_s * 8]) = br[r];
        __syncthreads();   // (b) LDS visible; no vmem outstanding here

        // issue next tile's global loads now -> in flight across the MFMA phase
        if (kt + 1 < ksteps) {
            const int k0n = (kt + 1) << 5;
#pragma unroll
            for (int r = 0; r < 4; ++r) ar[r] = *(const f32x4*)(Ap0 + (size_t)(32 * r) * K + k0n);
#pragma unroll
            for (int r = 0; r < 2; ++r) br[r] = *(const bf16x8*)(Bp0 + (size_t)(64 * r) * K + k0n);
        }

        bf16x8 afr[4], bfr[4];
#pragma unroll
        for (int mi = 0; mi < 4; ++mi)
            afr[mi] = *(const bf16x8*)(&sA[(wm + mi * 16 + l15) * 32 + q * 8]);
#pragma unroll
        for (int ni = 0; ni < 4; ++ni)
            bfr[ni] = *(const bf16x8*)(&sB[(wn + ni * 16 + l15) * 32 + q * 8]);
#pragma unroll
        for (int mi = 0; mi < 4; ++mi)
#pragma unroll
            for (int ni = 0; ni < 4; ++ni)
                acc[mi][ni] = __builtin_amdgcn_mfma_f32_16x16x32_bf16(bfr[ni], afr[mi], acc[mi][ni], 0, 0, 0);
    }

    // ---- epilogue ----
    // swapped C/D map: m = l15, channel = q*4 + reg  -> 8B packed stores, f32x4 bias
    __syncthreads();                       // everyone done with LDS tiles; reuse sA for reduction
    float* red = (float*)sA;               // [wmi][arr][128] = 2KiB
    const int wmi = wave >> 1;

#pragma unroll
    for (int ni = 0; ni < 4; ++ni) {
        const int chl = wn + ni * 16 + (q << 2);   // channel within block (0..127)
        const int nb = n0 + chl;
        f32x4 bv = *(const f32x4*)(bias + nb);
        f32x4 s1 = (f32x4){0.f, 0.f, 0.f, 0.f};
        f32x4 s2 = (f32x4){0.f, 0.f, 0.f, 0.f};
#pragma unroll
        for (int mi = 0; mi < 4; ++mi) {
            f32x4 v = acc[mi][ni] + bv;
            s1 += v;
            s2 += v * v;
            bf16x4 pk;
            pk[0] = (short)f2bf(v[0]); pk[1] = (short)f2bf(v[1]);
            pk[2] = (short)f2bf(v[2]); pk[3] = (short)f2bf(v[3]);
            *(bf16x4*)(&outb[(size_t)(m0 + wm + mi * 16 + l15) * N + nb]) = pk;
        }
        // reduce over the 16 rows held across l15 (butterfly keeps q bits fixed)
#pragma unroll
        for (int e = 0; e < 4; ++e) {
            s1[e] += __shfl_xor(s1[e], 1); s2[e] += __shfl_xor(s2[e], 1);
            s1[e] += __shfl_xor(s1[e], 2); s2[e] += __shfl_xor(s2[e], 2);
            s1[e] += __shfl_xor(s1[e], 4); s2[e] += __shfl_xor(s2[e], 4);
            s1[e] += __shfl_xor(s1[e], 8); s2[e] += __shfl_xor(s2[e], 8);
        }
        if (l15 == 0) {   // each wave owns disjoint channels per wmi -> plain stores
            *(f32x4*)(&red[(wmi * 2 + 0) * 128 + chl]) = s1;
            *(f32x4*)(&red[(wmi * 2 + 1) * 128 + chl]) = s2;
        }
    }
    __syncthreads();
    {
        const int arr = tid >> 7;          // 0 = sum, 1 = sumsq
        const int ch = tid & 127;
        float v = red[arr * 128 + ch] + red[(2 + arr) * 128 + ch];
        Ppart[((size_t)blockIdx.y * 2 + arr) * N + n0 + ch] = v;   // non-atomic
    }
}

// ---- reduce per-block partials into stats[4*Cout] (few atomics, coalesced reads) ----
extern "C" __global__ void reduce_kernel(const float* __restrict__ P1, const float* __restrict__ P2,
                                         float* __restrict__ stats, int gx1, int gx2, int nb1, int Cout)
{
    const int b = blockIdx.x;
    const int t = threadIdx.x;   // 0..Cout-1
    const float* P;
    int r0, rows, so;
    if (b < nb1) { P = P1; r0 = b * 64;        rows = gx1 - r0; so = 0; }
    else         { P = P2; r0 = (b - nb1) * 64; rows = gx2 - r0; so = 2 * Cout; }
    if (rows > 64) rows = 64;
    const int rw = 2 * Cout;
    float a0 = 0.f, a1 = 0.f;
    for (int r = 0; r < rows; ++r) {
        const float* row = P + (size_t)(r0 + r) * rw;
        a0 += row[t];
        a1 += row[Cout + t];
    }
    atomicAdd(&stats[so + t], a0);
    atomicAdd(&stats[so + Cout + t], a1);
}

// ---- per-channel BN affine: a = gamma*rsqrt(var+eps), b = beta - mean*a ----
extern "C" __global__ void finalize_kernel(const float* __restrict__ stats,
                                           const float* __restrict__ gamma_p, const float* __restrict__ beta_p,
                                           const float* __restrict__ gamma_s, const float* __restrict__ beta_s,
                                           float* __restrict__ ab, float invNp, float invNs, int Cout)
{
    int c = threadIdx.x;
    if (c < Cout) {
        float m = stats[c] * invNp;
        float var = stats[Cout + c] * invNp - m * m;
        float a = gamma_p[c] * rsqrtf(var + 1e-5f);
        ab[c] = a;
        ab[Cout + c] = beta_p[c] - m * a;
        float m2 = stats[2 * Cout + c] * invNs;
        float var2 = stats[3 * Cout + c] * invNs - m2 * m2;
        float a2 = gamma_s[c] * rsqrtf(var2 + 1e-5f);
        ab[2 * Cout + c] = a2;
        ab[3 * Cout + c] = beta_s[c] - m2 * a2;
    }
}

// ---- out[i,c] = relu(h[cluster[i],c]*ap+bp) + relu(s[i,c]*as+bs) ----
// assumes Cout == 256 (64 threads of 4 channels per point)
extern "C" __global__ __launch_bounds__(256)
void fuse_kernel(const unsigned short* __restrict__ hb, const unsigned short* __restrict__ sb,
                 const int* __restrict__ cluster, const float* __restrict__ ab,
                 float* __restrict__ out, int Cout)
{
    int idx = blockIdx.x * 256 + threadIdx.x;
    int i = idx >> 6;
    int c4 = (idx & 63) << 2;
    int j = cluster[i];
    bf16x4 h4 = *(const bf16x4*)(hb + (size_t)j * Cout + c4);
    bf16x4 s4 = *(const bf16x4*)(sb + (size_t)i * Cout + c4);
    f32x4 ap = *(const f32x4*)(ab + c4);
    f32x4 bp = *(const f32x4*)(ab + Cout + c4);
    f32x4 as = *(const f32x4*)(ab + 2 * Cout + c4);
    f32x4 bs = *(const f32x4*)(ab + 3 * Cout + c4);
    f32x4 o;
#pragma unroll
    for (int e = 0; e < 4; ++e) {
        float hv = bf2f((unsigned short)h4[e]) * ap[e] + bp[e];
        float sv = bf2f((unsigned short)s4[e]) * as[e] + bs[e];
        o[e] = fmaxf(hv, 0.f) + fmaxf(sv, 0.f);
    }
    *(f32x4*)(out + (size_t)i * Cout + c4) = o;
}

extern "C" void kernel_launch(void* const* d_in, const int* in_sizes, int n_in,
                              void* d_out, int out_size, void* d_ws, size_t ws_size,
                              hipStream_t stream)
{
    const float* feat    = (const float*)d_in[0];
    const float* skipf   = (const float*)d_in[1];
    const int*   cluster = (const int*)d_in[2];
    const float* W_proj  = (const float*)d_in[3];
    const float* b_proj  = (const float*)d_in[4];
    const float* gamma_p = (const float*)d_in[5];
    const float* beta_p  = (const float*)d_in[6];
    const float* W_skip  = (const float*)d_in[7];
    const float* b_skip  = (const float*)d_in[8];
    const float* gamma_s = (const float*)d_in[9];
    const float* beta_s  = (const float*)d_in[10];
    float* out = (float*)d_out;

    const int Cout = in_sizes[4];            // 256
    const int Cin  = in_sizes[3] / Cout;     // 512
    const int Cs   = in_sizes[7] / Cout;     // 256
    const int Nout = in_sizes[2];            // 262144
    const int Nin  = in_sizes[0] / Cin;      // 65536

    const int gx1 = Nin / 128;               // 512
    const int gx2 = Nout / 128;              // 2048

    // workspace layout (all offsets 16B-aligned) -- identical footprint to the
    // 820us-proven layout (~160.4 MiB); partials/stats live in d_out scratch.
    char* ws = (char*)d_ws;
    unsigned short* h_pre = (unsigned short*)ws; ws += (size_t)Nin * Cout * 2;        // 32 MiB
    unsigned short* s_pre = (unsigned short*)ws; ws += (size_t)Nout * Cout * 2;       // 128 MiB
    unsigned short* WpT   = (unsigned short*)ws; ws += (size_t)Cout * Cin * 2;        // 256 KiB
    unsigned short* WsT   = (unsigned short*)ws; ws += (size_t)Cout * Cs * 2;         // 128 KiB
    float* ab             = (float*)ws;                                               // 4 KiB (read during fuse)

    // scratch carved from d_out (256 MiB, fully overwritten by fuse_kernel at the end):
    // P1 (1 MiB) + P2 (4 MiB) + stats (4 KiB) are dead before fuse_kernel runs.
    float* P1    = out;
    float* P2    = P1 + (size_t)gx1 * 2 * Cout;
    float* stats = P2 + (size_t)gx2 * 2 * Cout;

    hipMemsetAsync(stats, 0, 4 * Cout * sizeof(float), stream);

    int prep_total = Cin * Cout + Cs * Cout;
    prep_w_kernel<<<(prep_total + 255) / 256, 256, 0, stream>>>(W_proj, W_skip, WpT, WsT, Cin, Cs, Cout);

    dim3 g1(Cout / 128, gx1);
    gemm_bn_kernel<<<g1, 256, 0, stream>>>(feat, WpT, b_proj, h_pre, P1, Nin, Cin, Cout);

    dim3 g2(Cout / 128, gx2);
    gemm_bn_kernel<<<g2, 256, 0, stream>>>(skipf, WsT, b_skip, s_pre, P2, Nout, Cs, Cout);

    const int nb1 = (gx1 + 63) / 64;
    const int nb2 = (gx2 + 63) / 64;
    reduce_kernel<<<nb1 + nb2, 256, 0, stream>>>(P1, P2, stats, gx1, gx2, nb1, Cout);

    finalize_kernel<<<1, Cout, 0, stream>>>(stats, gamma_p, beta_p, gamma_s, beta_s,
                                            ab, 1.0f / (float)Nin, 1.0f / (float)Nout, Cout);

    size_t total_threads = (size_t)Nout * (Cout / 4);
    fuse_kernel<<<(unsigned)(total_threads / 256), 256, 0, stream>>>(h_pre, s_pre, cluster, ab, out, Cout);
}